// Round 5
// baseline (82.935 us; speedup 1.0000x reference)
//
#include <hip/hip_runtime.h>
#include <hip/hip_bf16.h>
#include <stdint.h>

// LSTMCell: B=64, T=256, D=32, N=64.
// gate[b,d,m] = sum_n h[b,d,n]*W[d,n,m] + x[b,t,d]*U[d,m] + bias[d,m]
//
// Topology (proven 80.2-80.7us): 512 blocks = 32d x 16 batch-tiles of 4,
// 4 waves/block, 2048 waves = 2 blocks/CU, 2 waves/SIMD from DIFFERENT
// blocks. Batches at MFMA rows {0,4,8,12}: each lane owns 1 element
// (batch g, col mcol) in acc reg 0; junk A rows (quad-broadcast) feed only
// never-read C regs 1..3.
//
// R16 = R15 + two critical-path latency cuts. Evidence to date:
//   - R10/R11/R14 (3 stagger mechanisms incl. physical HW_ID slot parity):
//     null -> anti-phase is dynamically unstable (in-phase lock attractor).
//   - R12 (1 block/CU + in-step ILP): +41% -> chain hidden only ACROSS blocks.
//   - R13 (both-zero-C + 3-way add join): +7% -> keep the early VALU seed.
//   - R15 (trans 10->8): wall neutral, VALUBusy -2pt -> step is LATENCY-
//     bound on the serial recurrence chain; VALU issue has slack.
// Remaining lever = the chain itself:
//   (1) HYBRID MFMA: accA = mfma(a0,w0,seeded-C) chained as before;
//       accB = mfma(a1,w1,0) independent; gate = accA[0]+accB[0].
//       Latency L+4 instead of 2L (~15-30 cy/step). One add per gate.
//   (2) out[] store DEFERRED past the barrier into the next step's
//       ds_read shadow (dead latency cycles); removes it from the
//       pre-drain window. h_prev/oprev bookkeeping, uniform if(t>0).
//
// Merged-rcp activations kept from R15 (8 trans, exact algebra):
//   i*j = (Ej-1)/[(Ej+1)(1+Ei)],  c' = c*rcp(1+Ef) + i*j,
//   h = (Ec-1)/[(Ec+1)(1+Eo)].  |gate| <~ 1.6 -> no overflow path.
//
// MFMA k-placement: logical k=8g+j in slot (g,j) for BOTH A and B -> exact
// dot product under any HW slot->k bijection. C/D layout (HW-verified):
// col=lane&15, row=4*(lane>>4)+reg.
//
// Barrier: lgkmcnt-only drain + raw s_barrier (NOT __syncthreads: vmcnt(0)
// would pull the fire-and-forget global h stores into the critical path).
// setprio head/tail kept (R9: +2%).

typedef __attribute__((ext_vector_type(8))) __bf16 bf16x8;
typedef __attribute__((ext_vector_type(4))) float f32x4;

union FragU { uint4 u; bf16x8 v; };

__global__ __launch_bounds__(256, 2) void lstm_kernel(
    const float* __restrict__ x,
    const float* __restrict__ Wj, const float* __restrict__ Wi,
    const float* __restrict__ Wf, const float* __restrict__ Wo,
    const float* __restrict__ Uj, const float* __restrict__ Ui,
    const float* __restrict__ Uf, const float* __restrict__ Uo,
    const float* __restrict__ bj, const float* __restrict__ bi,
    const float* __restrict__ bf, const float* __restrict__ bo,
    float* __restrict__ out)
{
    constexpr int T = 256, D = 32, N = 64, B = 64;
    const int bid   = blockIdx.x;     // 0..511
    const int d     = bid >> 4;       // 0..31
    const int btile = bid & 15;       // 0..15 (4 batches each)
    const int tid   = threadIdx.x;
    const int w     = tid >> 6;       // wave 0..3
    const int lane  = tid & 63;
    const int g     = lane >> 4;      // lane group 0..3
    const int li    = lane & 15;
    const int mcol  = w * 16 + li;    // output feature owned by this lane

    // Compact h exchange: [buf][batch r][64 cols, 16B-chunk-swizzled
    // p = (chunk + 2r) & 7].
    __shared__ __align__(16) __bf16 hbuf[2][4][64];
    __shared__ float xs[4][256];      // x[batch][t] for this (d, btile)

    for (int idx = tid; idx < 2 * 4 * 64; idx += 256)
        (&hbuf[0][0][0])[idx] = (__bf16)0.0f;          // h0 = 0
    for (int idx = tid; idx < 4 * 256; idx += 256) {
        int bl = idx >> 8, t = idx & 255;
        xs[bl][t] = x[((size_t)(btile * 4 + bl) * T + t) * D + d];
    }

    // Persistent per-lane operands: W B-fragments (32 VGPR), U, bias.
    const float* Wg[4] = { Wj, Wi, Wf, Wo };
    const float* Ug[4] = { Uj, Ui, Uf, Uo };
    const float* Bg[4] = { bj, bi, bf, bo };
    FragU wfrag[4][2];
    float uv[4], bv[4];
    #pragma unroll
    for (int G = 0; G < 4; ++G) {
        uv[G] = Ug[G][d * N + mcol];
        bv[G] = Bg[G][d * N + mcol];
        const float* base = Wg[G] + (size_t)d * N * N + mcol;
        #pragma unroll
        for (int f = 0; f < 2; ++f) {
            const int k0 = f * 32 + g * 8;
            bf16x8 tmp;
            #pragma unroll
            for (int j = 0; j < 8; ++j)
                tmp[j] = (__bf16)base[(size_t)(k0 + j) * N];  // W[d][k][m]
            wfrag[G][f].v = tmp;
        }
    }

    f32x4 acc[4];
    #pragma unroll
    for (int G = 0; G < 4; ++G)
        acc[G] = f32x4{ bv[G], bv[G], bv[G], bv[G] };

    // Loop-invariant zero C for the independent k-half-1 MFMAs.
    f32x4 zeroacc = f32x4{ 0.f, 0.f, 0.f, 0.f };

    // Writer: lane owns (batch g, col mcol) -> row g, swizzled chunk.
    const int cm = mcol >> 3;
    const int woff = (((cm + 2 * g) & 7) << 3) | (mcol & 7);
    __bf16* hw0 = &hbuf[0][g][0] + woff;
    __bf16* hw1 = &hbuf[1][g][0] + woff;

    // Reader (ALL lanes; quads broadcast their leader's address).
    const int rr = li >> 2;                   // A row quad -> batch rr
    const int p0 = (g + 2 * rr) & 7;          // logical chunk g
    const int p1 = (g + 4 + 2 * rr) & 7;      // logical chunk g+4
    const uint4* ra00 = (const uint4*)&hbuf[0][rr][p0 << 3];
    const uint4* ra01 = (const uint4*)&hbuf[1][rr][p0 << 3];
    const uint4* ra10 = (const uint4*)&hbuf[0][rr][p1 << 3];
    const uint4* ra11 = (const uint4*)&hbuf[1][rr][p1 << 3];

    __syncthreads();

    float c0 = 0.f, h0 = 0.f;
    float h_prev = 0.f;
    uint32_t oprev = 0;
    const int gb = btile * 4 + g;     // global batch
    uint32_t oidx = (uint32_t)gb * (T * D * N) + (uint32_t)(d * N + mcol);

    // exp(x) = exp2(K*x); exp(2x) = exp2(K2*x).
    constexpr float K  = 1.4426950408889634f;
    constexpr float K2 = 2.8853900817779268f;

    #pragma unroll 1
    for (int t = 0; t < T; t += 8) {
        const float4 xa = *(const float4*)&xs[g][t];
        const float4 xb = *(const float4*)&xs[g][t + 4];
        #pragma unroll
        for (int uu = 0; uu < 8; ++uu) {
            // CHAIN HEAD at high priority (R9 +2%).
            __builtin_amdgcn_s_setprio(1);
            const int rb = uu & 1;             // read buffer = tt&1
            FragU a0, a1;
            a0.u = *(rb ? ra01 : ra00);
            a1.u = *(rb ? ra11 : ra10);
            // Deferred out-store of the PREVIOUS step's h: fills the
            // post-barrier ds_read latency shadow (dead cycles).
            if (uu == 0) {
                if (t > 0) out[oprev] = h_prev;   // uniform branch, 1/8 steps
            } else {
                out[oprev] = h_prev;
            }
            const float xv = (uu < 4) ? xa[uu] : xb[uu - 4];
            #pragma unroll
            for (int G = 0; G < 4; ++G)
                acc[G][0] = __builtin_fmaf(xv, uv[G], bv[G]);
            // HYBRID accumulate: k-half 0 chained into seeded acc (early
            // seed, as R11); k-half 1 independent zero-C; join = 1 add.
            // Latency L+4 instead of 2L.
            f32x4 accB[4];
            #pragma unroll
            for (int G = 0; G < 4; ++G) {
                acc[G]  = __builtin_amdgcn_mfma_f32_16x16x32_bf16(a0.v, wfrag[G][0].v, acc[G], 0, 0, 0);
                accB[G] = __builtin_amdgcn_mfma_f32_16x16x32_bf16(a1.v, wfrag[G][1].v, zeroacc, 0, 0, 0);
            }
            const float gj = acc[0][0] + accB[0][0];
            const float gi = acc[1][0] + accB[1][0];
            const float gf = acc[2][0] + accB[2][0];
            const float go = acc[3][0] + accB[3][0];
            // Merged-rcp activations (8 trans). Exact algebra:
            //   i*j = (Ej-1)/[(Ej+1)(1+Ei)]
            //   c'  = c*rcp(1+Ef) + i*j
            //   h   = (Ec-1)/[(Ec+1)(1+Eo)]
            const float Ej = __builtin_amdgcn_exp2f( K2 * gj);
            const float Ei = __builtin_amdgcn_exp2f(-K  * gi);
            const float Ef = __builtin_amdgcn_exp2f(-K  * gf);
            const float Eo = __builtin_amdgcn_exp2f(-K  * go);
            const float Rij = __builtin_amdgcn_rcpf((Ej + 1.0f) * (1.0f + Ei));
            const float ij  = (Ej - 1.0f) * Rij;
            const float Rf  = __builtin_amdgcn_rcpf(1.0f + Ef);
            c0 = __builtin_fmaf(c0, Rf, ij);
            const float Ec = __builtin_amdgcn_exp2f(K2 * c0);
            const float Rh = __builtin_amdgcn_rcpf((Ec + 1.0f) * (1.0f + Eo));
            h0 = (Ec - 1.0f) * Rh;
            // TAIL at low priority.
            __builtin_amdgcn_s_setprio(0);
            *(rb ? hw0 : hw1) = (__bf16)h0;    // write NEXT buffer
            h_prev = h0;                       // store deferred to next step
            oprev = oidx;
            oidx += D * N;
            asm volatile("s_waitcnt lgkmcnt(0)" ::: "memory");
            __builtin_amdgcn_s_barrier();
        }
    }
    out[oprev] = h_prev;                       // final step's pending store

    // h_T (B,D,N) then c_T (B,D,N), appended after outputs.
    const size_t baseH = (size_t)B * T * D * N;
    const size_t baseC = baseH + (size_t)B * D * N;
    const size_t i0 = ((size_t)gb * D + d) * N + mcol;
    out[baseH + i0] = h0;
    out[baseC + i0] = c0;
}

extern "C" void kernel_launch(void* const* d_in, const int* in_sizes, int n_in,
                              void* d_out, int out_size, void* d_ws, size_t ws_size,
                              hipStream_t stream) {
    lstm_kernel<<<dim3(512), dim3(256), 0, stream>>>(
        (const float*)d_in[0],
        (const float*)d_in[1], (const float*)d_in[2],
        (const float*)d_in[3], (const float*)d_in[4],
        (const float*)d_in[5], (const float*)d_in[6],
        (const float*)d_in[7], (const float*)d_in[8],
        (const float*)d_in[9], (const float*)d_in[10],
        (const float*)d_in[11], (const float*)d_in[12],
        (float*)d_out);
}

// Round 6
// 81.154 us; speedup vs baseline: 1.0219x; 1.0219x over previous
//
#include <hip/hip_runtime.h>
#include <hip/hip_bf16.h>
#include <stdint.h>

// LSTMCell: B=64, T=256, D=32, N=64.
// gate[b,d,m] = sum_n h[b,d,n]*W[d,n,m] + x[b,t,d]*U[d,m] + bias[d,m]
//
// R17 = exact revert to R15, the best-measured variant (80.55us; family
// optimum 80.2-80.7us across R4/R9/R11/R15).
//
// Topology: 512 blocks = 32d x 16 batch-tiles of 4, 4 waves/block,
// 2048 waves = 2 blocks/CU, 2 waves/SIMD from DIFFERENT blocks. Batches
// at MFMA rows {0,4,8,12}: each lane owns 1 element (batch g, col mcol)
// in acc reg 0; junk A rows (quad-broadcast) feed only never-read C regs.
//
// Final accounting (fits all measured configs): per step the grid issues
// 16384 MFMAs x 19.4 cy/SIMD (16x16 ubench ceiling) + ~235k SIMD-cy
// VALU/trans => ~540 cy/SIMD-step issue floor at 4-row packing; measured
// 754 = floor + barrier/drain overlap loss. Denser row packing (8/16
// batches/tile) cuts MFMA volume but collapses parallelism to <=1 wave/
// SIMD -> chain-exposed (R12 measured 1095 cy/step). Measured lever map:
//   - stagger (hash x2, physical HW_ID parity): null (R10/R11/R14) --
//     in-phase lock of co-resident blocks is the dynamical attractor.
//   - 1 block/CU + in-step ILP: +41% (R12).
//   - zero-C split / hybrid MFMA: +7% / +3% (R13/R16) -- chained-seeded
//     MFMA with early VALU seed is the optimal dependency shape.
//   - trans 10->8 (merged rcp): wall-neutral, kept (R15).
//   - deferred out-store: +3% (R16) -- in-step fire-and-forget is best.
// => practical ceiling of this packing family ~80us; not a pipe roofline
// (MfmaUtil 29%, VALUBusy 44%) but a sync-latency/issue tradeoff minimum.
//
// Merged-rcp activations (8 trans, exact algebra):
//   i*j = (Ej-1)/[(Ej+1)(1+Ei)],  c' = c*rcp(1+Ef) + i*j,
//   h = (Ec-1)/[(Ec+1)(1+Eo)].  |gate| <~ 1.6 -> no overflow path.
//
// MFMA k-placement: logical k=8g+j in slot (g,j) for BOTH A and B -> exact
// dot product under any HW slot->k bijection. C/D layout (HW-verified):
// col=lane&15, row=4*(lane>>4)+reg.
//
// Barrier: lgkmcnt-only drain + raw s_barrier (NOT __syncthreads: vmcnt(0)
// would pull the fire-and-forget global h stores into the critical path).
// setprio head/tail kept (R9: +2%).

typedef __attribute__((ext_vector_type(8))) __bf16 bf16x8;
typedef __attribute__((ext_vector_type(4))) float f32x4;

union FragU { uint4 u; bf16x8 v; };

__global__ __launch_bounds__(256, 2) void lstm_kernel(
    const float* __restrict__ x,
    const float* __restrict__ Wj, const float* __restrict__ Wi,
    const float* __restrict__ Wf, const float* __restrict__ Wo,
    const float* __restrict__ Uj, const float* __restrict__ Ui,
    const float* __restrict__ Uf, const float* __restrict__ Uo,
    const float* __restrict__ bj, const float* __restrict__ bi,
    const float* __restrict__ bf, const float* __restrict__ bo,
    float* __restrict__ out)
{
    constexpr int T = 256, D = 32, N = 64, B = 64;
    const int bid   = blockIdx.x;     // 0..511
    const int d     = bid >> 4;       // 0..31
    const int btile = bid & 15;       // 0..15 (4 batches each)
    const int tid   = threadIdx.x;
    const int w     = tid >> 6;       // wave 0..3
    const int lane  = tid & 63;
    const int g     = lane >> 4;      // lane group 0..3
    const int li    = lane & 15;
    const int mcol  = w * 16 + li;    // output feature owned by this lane

    // Compact h exchange: [buf][batch r][64 cols, 16B-chunk-swizzled
    // p = (chunk + 2r) & 7].
    __shared__ __align__(16) __bf16 hbuf[2][4][64];
    __shared__ float xs[4][256];      // x[batch][t] for this (d, btile)

    for (int idx = tid; idx < 2 * 4 * 64; idx += 256)
        (&hbuf[0][0][0])[idx] = (__bf16)0.0f;          // h0 = 0
    for (int idx = tid; idx < 4 * 256; idx += 256) {
        int bl = idx >> 8, t = idx & 255;
        xs[bl][t] = x[((size_t)(btile * 4 + bl) * T + t) * D + d];
    }

    // Persistent per-lane operands: W B-fragments (32 VGPR), U, bias.
    const float* Wg[4] = { Wj, Wi, Wf, Wo };
    const float* Ug[4] = { Uj, Ui, Uf, Uo };
    const float* Bg[4] = { bj, bi, bf, bo };
    FragU wfrag[4][2];
    float uv[4], bv[4];
    #pragma unroll
    for (int G = 0; G < 4; ++G) {
        uv[G] = Ug[G][d * N + mcol];
        bv[G] = Bg[G][d * N + mcol];
        const float* base = Wg[G] + (size_t)d * N * N + mcol;
        #pragma unroll
        for (int f = 0; f < 2; ++f) {
            const int k0 = f * 32 + g * 8;
            bf16x8 tmp;
            #pragma unroll
            for (int j = 0; j < 8; ++j)
                tmp[j] = (__bf16)base[(size_t)(k0 + j) * N];  // W[d][k][m]
            wfrag[G][f].v = tmp;
        }
    }

    f32x4 acc[4];
    #pragma unroll
    for (int G = 0; G < 4; ++G)
        acc[G] = f32x4{ bv[G], bv[G], bv[G], bv[G] };

    // Writer: lane owns (batch g, col mcol) -> row g, swizzled chunk.
    const int cm = mcol >> 3;
    const int woff = (((cm + 2 * g) & 7) << 3) | (mcol & 7);
    __bf16* hw0 = &hbuf[0][g][0] + woff;
    __bf16* hw1 = &hbuf[1][g][0] + woff;

    // Reader (ALL lanes; quads broadcast their leader's address).
    const int rr = li >> 2;                   // A row quad -> batch rr
    const int p0 = (g + 2 * rr) & 7;          // logical chunk g
    const int p1 = (g + 4 + 2 * rr) & 7;      // logical chunk g+4
    const uint4* ra00 = (const uint4*)&hbuf[0][rr][p0 << 3];
    const uint4* ra01 = (const uint4*)&hbuf[1][rr][p0 << 3];
    const uint4* ra10 = (const uint4*)&hbuf[0][rr][p1 << 3];
    const uint4* ra11 = (const uint4*)&hbuf[1][rr][p1 << 3];

    __syncthreads();

    float c0 = 0.f, h0 = 0.f;
    const int gb = btile * 4 + g;     // global batch
    uint32_t oidx = (uint32_t)gb * (T * D * N) + (uint32_t)(d * N + mcol);

    // exp(x) = exp2(K*x); exp(2x) = exp2(K2*x).
    constexpr float K  = 1.4426950408889634f;
    constexpr float K2 = 2.8853900817779268f;

    #pragma unroll 1
    for (int t = 0; t < T; t += 8) {
        const float4 xa = *(const float4*)&xs[g][t];
        const float4 xb = *(const float4*)&xs[g][t + 4];
        #pragma unroll
        for (int uu = 0; uu < 8; ++uu) {
            // CHAIN HEAD at high priority (R9 +2%).
            __builtin_amdgcn_s_setprio(1);
            const int rb = uu & 1;             // read buffer = tt&1
            FragU a0, a1;
            a0.u = *(rb ? ra01 : ra00);
            a1.u = *(rb ? ra11 : ra10);
            const float xv = (uu < 4) ? xa[uu] : xb[uu - 4];
            #pragma unroll
            for (int G = 0; G < 4; ++G)
                acc[G][0] = __builtin_fmaf(xv, uv[G], bv[G]);
            #pragma unroll
            for (int G = 0; G < 4; ++G) {
                acc[G] = __builtin_amdgcn_mfma_f32_16x16x32_bf16(a0.v, wfrag[G][0].v, acc[G], 0, 0, 0);
                acc[G] = __builtin_amdgcn_mfma_f32_16x16x32_bf16(a1.v, wfrag[G][1].v, acc[G], 0, 0, 0);
            }
            // Merged-rcp activations (8 trans, was 10). Exact algebra:
            //   j = tanh(gj) = (Ej-1)/(Ej+1),  Ej = exp(2*gj)
            //   i = 1/(1+Ei), Ei = exp(-gi);  f,o likewise
            //   i*j = (Ej-1)/[(Ej+1)(1+Ei)]
            //   c'  = c*rcp(1+Ef) + i*j
            //   h   = o*tanh(c') = (Ec-1)/[(Ec+1)(1+Eo)], Ec = exp(2*c')
            const float Ej = __builtin_amdgcn_exp2f( K2 * acc[0][0]);
            const float Ei = __builtin_amdgcn_exp2f(-K  * acc[1][0]);
            const float Ef = __builtin_amdgcn_exp2f(-K  * acc[2][0]);
            const float Eo = __builtin_amdgcn_exp2f(-K  * acc[3][0]);
            const float Rij = __builtin_amdgcn_rcpf((Ej + 1.0f) * (1.0f + Ei));
            const float ij  = (Ej - 1.0f) * Rij;
            const float Rf  = __builtin_amdgcn_rcpf(1.0f + Ef);
            c0 = __builtin_fmaf(c0, Rf, ij);
            const float Ec = __builtin_amdgcn_exp2f(K2 * c0);
            const float Rh = __builtin_amdgcn_rcpf((Ec + 1.0f) * (1.0f + Eo));
            h0 = (Ec - 1.0f) * Rh;
            // TAIL at low priority.
            __builtin_amdgcn_s_setprio(0);
            *(rb ? hw0 : hw1) = (__bf16)h0;    // write NEXT buffer
            out[oidx] = h0;                    // fire-and-forget (drain shadow)
            oidx += D * N;
            asm volatile("s_waitcnt lgkmcnt(0)" ::: "memory");
            __builtin_amdgcn_s_barrier();
        }
    }

    // h_T (B,D,N) then c_T (B,D,N), appended after outputs.
    const size_t baseH = (size_t)B * T * D * N;
    const size_t baseC = baseH + (size_t)B * D * N;
    const size_t i0 = ((size_t)gb * D + d) * N + mcol;
    out[baseH + i0] = h0;
    out[baseC + i0] = c0;
}

extern "C" void kernel_launch(void* const* d_in, const int* in_sizes, int n_in,
                              void* d_out, int out_size, void* d_ws, size_t ws_size,
                              hipStream_t stream) {
    lstm_kernel<<<dim3(512), dim3(256), 0, stream>>>(
        (const float*)d_in[0],
        (const float*)d_in[1], (const float*)d_in[2],
        (const float*)d_in[3], (const float*)d_in[4],
        (const float*)d_in[5], (const float*)d_in[6],
        (const float*)d_in[7], (const float*)d_in[8],
        (const float*)d_in[9], (const float*)d_in[10],
        (const float*)d_in[11], (const float*)d_in[12],
        (float*)d_out);
}